// Round 4
// baseline (248.127 us; speedup 1.0000x reference)
//
#include <hip/hip_runtime.h>

// Full 2D convolution: in (32,16,256,256) f32, shared 5x5 kernel, out (32,16,260,260) f32.
// out[n][y][x] = sum_{a,b in [0,5)} in[n][y-a][x-b] * w[a][b]
//
// R4: register-pressure-tuned strip kernel. ROWS=5 outputs/thread; the 9-row x
// 8-float window (72 VGPRs) is written directly from 18 independent clamped
// float4 loads with masking fused into consumption (no separate raw arrays).
// __launch_bounds__(256,4) caps at 128 VGPR -> no spills, 16 waves/CU.
// In-flight bytes/CU ~ 16 waves * 18 loads * 16 B = 4.6 KB -> HBM-BW-bound.

#define IMG 256
#define OW  260
#define TXN 65           // float4s per output row
#define ROWS 5           // output rows per thread
#define WROWS 9          // input rows touched: ROWS + 4
#define STRIPS 52        // 260 / 5
#define NIMG 512         // 32*16 images
#define NTHREADS (NIMG * STRIPS * TXN)   // 1,730,560 = 6760 * 256

__global__ __launch_bounds__(256, 4) void conv_full_r4(
    const float* __restrict__ in, const float* __restrict__ w,
    float* __restrict__ out)
{
    // Shared 5x5 kernel — uniform address, lands in SGPRs.
    float wt[25];
#pragma unroll
    for (int i = 0; i < 25; ++i) wt[i] = w[i];

    int idx = blockIdx.x * 256 + threadIdx.x;
    int tx4 = idx % TXN;
    int t   = idx / TXN;
    int s   = t % STRIPS;
    int n   = t / STRIPS;
    int y0  = s * ROWS;
    int x0  = tx4 * 4;

    // Clamped, always-in-bounds 16B-aligned load columns; edge lanes zeroed
    // branch-free below.
    int xl = x0 - 4; if (xl < 0) xl = 0;
    int xh = x0;     if (xh > IMG - 4) xh = IMG - 4;
    const bool zL = (tx4 == 0);
    const bool zR = (tx4 == TXN - 1);

    const float* img = in + (size_t)n * IMG * IMG;

    // 9-row x 8-float window, written straight from 18 independent loads.
    // All loads are unconditional (clamped row), so the compiler can issue
    // them back-to-back; selects wait on vmcnt afterwards.
    float v[WROWS][8];
#pragma unroll
    for (int r = 0; r < WROWS; ++r) {
        int yy = y0 + r - 4;
        int yc = yy < 0 ? 0 : (yy > IMG - 1 ? IMG - 1 : yy);
        const float* rb = img + yc * IMG;
        float4 lo = *(const float4*)(rb + xl);
        float4 hi = *(const float4*)(rb + xh);
        bool rv = (yy >= 0) & (yy < IMG);
        bool mL = rv & !zL;
        bool mR = rv & !zR;
        v[r][0] = mL ? lo.x : 0.f;
        v[r][1] = mL ? lo.y : 0.f;
        v[r][2] = mL ? lo.z : 0.f;
        v[r][3] = mL ? lo.w : 0.f;
        v[r][4] = mR ? hi.x : 0.f;
        v[r][5] = mR ? hi.y : 0.f;
        v[r][6] = mR ? hi.z : 0.f;
        v[r][7] = mR ? hi.w : 0.f;
    }

    float* outp = out + (((size_t)n * OW + y0) * TXN + tx4) * 4;
#pragma unroll
    for (int r = 0; r < ROWS; ++r) {
        float acc0 = 0.f, acc1 = 0.f, acc2 = 0.f, acc3 = 0.f;
#pragma unroll
        for (int a = 0; a < 5; ++a) {
            const float* vv = v[r + 4 - a];   // input row y0 + r - a
#pragma unroll
            for (int b = 0; b < 5; ++b) {
                float wv = wt[a * 5 + b];
                acc0 = fmaf(vv[4 - b], wv, acc0);
                acc1 = fmaf(vv[5 - b], wv, acc1);
                acc2 = fmaf(vv[6 - b], wv, acc2);
                acc3 = fmaf(vv[7 - b], wv, acc3);
            }
        }
        *(float4*)(outp + (size_t)r * OW) = make_float4(acc0, acc1, acc2, acc3);
    }
}

extern "C" void kernel_launch(void* const* d_in, const int* in_sizes, int n_in,
                              void* d_out, int out_size, void* d_ws, size_t ws_size,
                              hipStream_t stream) {
    const float* in = (const float*)d_in[0];   // 32*16*256*256 f32
    const float* w  = (const float*)d_in[1];   // 5*5 f32
    float* out = (float*)d_out;                // 32*16*260*260 f32

    int blocks = NTHREADS / 256;               // exactly 6760
    conv_full_r4<<<blocks, 256, 0, stream>>>(in, w, out);
}